// Round 1
// baseline (321.012 us; speedup 1.0000x reference)
//
#include <hip/hip_runtime.h>
#include <hip/hip_bf16.h>
#include <cstddef>
#include <cstdint>

#define B_    16
#define CIN_  256
#define COUT_ 128
#define H_    64
#define W_    64
#define OH_   128
#define OW_   128

// A-matrix row stride in shorts: 32 real k-values + 12 pad (bank-conflict fix).
// Stride 44 shorts = 88 B -> bank start (22*nlo) % 32 covers all 16 even
// positions (2-way only, free) vs stride 40 (80 B) which hit 8 -> 4-way.
#define AST   44
#define ACHUNK (128*AST)          // shorts per (cls,chunk) A slice = 5632
#define ABYTES (ACHUNK*2)         // 11264 B = 11 x 1KB wave transfers

typedef __attribute__((ext_vector_type(8))) short bf16x8;
typedef __attribute__((ext_vector_type(4))) float f32x4;

__device__ inline short f2bf(float f) {
    __hip_bfloat16 h = __float2bfloat16(f);
    return *reinterpret_cast<short*>(&h);
}

__device__ inline void async_ld16(const void* g, void* l) {
    typedef const __attribute__((address_space(1))) unsigned int* gp_t;
    typedef __attribute__((address_space(3))) unsigned int* lp_t;
    __builtin_amdgcn_global_load_lds((gp_t)g, (lp_t)l, 16, 0, 0);
}

// ---------------------------------------------------------------------------
// Synth body: per-(b,cls) weight matrices in MFMA A-layout, row stride AST.
// aws[b][cls(4)][chunk(32)][co(128)][AST] bf16; k_local = t*8 + ci_l,
// t = dh*2+dw; kh -> r=(kh+1)&1, dh=(kh<2); cls = r*2+s. k 32..43 = pad (junk).
// ---------------------------------------------------------------------------
__device__ inline void synth_body(
    int chunk, int cog, int b, int tid,
    const float* __restrict__ weight,
    const float* __restrict__ tb, const float* __restrict__ tq,
    const float* __restrict__ tn, const float* __restrict__ tx,
    const float* __restrict__ mb, const float* __restrict__ mq,
    const float* __restrict__ mn, const float* __restrict__ mx,
    const float* __restrict__ feat,
    short* __restrict__ aws,
    short* lbuf /* [4][32][AST] shorts, 16B aligned */)
{
    const int ci0 = chunk * 8;
    const float f0 = feat[b*4+0], f1 = feat[b*4+1];
    const float f2 = feat[b*4+2], f3 = feat[b*4+3];

    #pragma unroll
    for (int it = 0; it < 4; ++it) {
        int e4   = tid + it*256;          // 0..1023: (ci_l, co_l, kh)
        int ci_l = e4 >> 7;
        int rem  = e4 & 127;
        int co_l = rem >> 2;
        int kh   = rem & 3;
        int co   = cog*32 + co_l;
        int base = (ci0 + ci_l) * COUT_ + co;
        float4 w4 = *(const float4*)(weight + (size_t)base*16 + kh*4);
        float4 b4 = *(const float4*)(tb + (size_t)base*16 + kh*4);
        float4 q4 = *(const float4*)(tq + (size_t)base*16 + kh*4);
        float4 n4 = *(const float4*)(tn + (size_t)base*16 + kh*4);
        float4 x4 = *(const float4*)(tx + (size_t)base*16 + kh*4);
        const float* wp = (const float*)&w4;
        const float* bp = (const float*)&b4;
        const float* qp = (const float*)&q4;
        const float* np = (const float*)&n4;
        const float* xp = (const float*)&x4;
        float sb = mb[base]*f0, sq = mq[base]*f1;
        float sn = mn[base]*f2, sx = mx[base]*f3;
        int r  = (kh+1)&1;
        int dh = (kh<2) ? 1 : 0;
        #pragma unroll
        for (int kw = 0; kw < 4; ++kw) {
            int s  = (kw+1)&1;
            int dw = (kw<2) ? 1 : 0;
            float v = wp[kw] + sb*bp[kw] + sq*qp[kw] + sn*np[kw] + sx*xp[kw];
            lbuf[((r*2+s)*32 + co_l)*AST + (dh*2+dw)*8 + ci_l] = f2bf(v);
        }
    }
    __syncthreads();
    // coalesced copy-out: per cls a contiguous 32*AST*2 = 2816 B slice
    for (int j = tid; j < 4*176; j += 256) {          // 176 = 32*AST/8 int4s
        int cls = j / 176; int jj = j - cls*176;
        size_t dst = (((size_t)(b*4 + cls)*32 + chunk)*128 + cog*32) * AST;
        *(int4*)(aws + dst + (size_t)jj*8) =
            *(const int4*)(lbuf + cls*32*AST + jj*8);
    }
}

// ---------------------------------------------------------------------------
// Transform body: x (fp32 NCHW) -> x_t bf16 [b][chunk32][ihp66][iwp66][ci8]
// with zero halo. float4 x-loads (16B/lane) + padded [128][68] LDS transpose.
// ---------------------------------------------------------------------------
__device__ inline void transform_body(
    int ihp, int b, int tid,
    const float* __restrict__ x, short* __restrict__ xt,
    float* xls /* [128][68] floats */)
{
    const int4 z4 = {0, 0, 0, 0};

    if (ihp == 0 || ihp == 65) {       // border rows: zero all chunks/cols
        for (int j = tid; j < 2112; j += 256) {       // 32 chunks * 66 cols
            int c = j / 66, iwp = j - c*66;
            *(int4*)(xt + ((((size_t)b*32 + c)*66 + ihp)*66 + iwp)*8) = z4;
        }
        return;
    }
    if (tid < 64) {                    // border cols iwp in {0,65}
        int c = tid >> 1, iwp = (tid & 1) * 65;
        *(int4*)(xt + ((((size_t)b*32 + c)*66 + ihp)*66 + iwp)*8) = z4;
    }
    const int ih = ihp - 1;
    for (int half = 0; half < 2; ++half) {
        __syncthreads();
        // stage 128 ci x 64 iw via float4 (8 iters x 4KB)
        #pragma unroll
        for (int it = 0; it < 8; ++it) {
            int ci_l = it*16 + (tid >> 4);
            int iw4  = (tid & 15) * 4;
            float4 v = *(const float4*)(
                x + (((size_t)b*256 + half*128 + ci_l)*64 + ih)*64 + iw4);
            *(float4*)(xls + ci_l*68 + iw4) = v;
        }
        __syncthreads();
        #pragma unroll
        for (int it2 = 0; it2 < 4; ++it2) {
            int chunk_l = it2*4 + (tid >> 6);
            int chunk   = half*16 + chunk_l;
            int iw      = tid & 63;
            short s8[8];
            #pragma unroll
            for (int j = 0; j < 8; ++j)
                s8[j] = f2bf(xls[(chunk_l*8 + j)*68 + iw]);
            *(int4*)(xt + ((((size_t)b*32 + chunk)*66 + ihp)*66 + (iw+1))*8)
                = *(const int4*)s8;
        }
    }
}

// ---------------------------------------------------------------------------
// Fused prep: transform blocks [0,1056) + synth blocks [1056,3104).
// The two jobs are independent; fusing them overlaps their execution and
// drops one kernel launch.
// ---------------------------------------------------------------------------
__global__ __launch_bounds__(256) void prep_fused(
    const float* __restrict__ x,
    const float* __restrict__ weight,
    const float* __restrict__ tb, const float* __restrict__ tq,
    const float* __restrict__ tn, const float* __restrict__ tx,
    const float* __restrict__ mb, const float* __restrict__ mq,
    const float* __restrict__ mn, const float* __restrict__ mx,
    const float* __restrict__ feat,
    short* __restrict__ aws, short* __restrict__ xt)
{
    __shared__ __align__(16) char smem[34816];   // max(11264 synth, 34816 xfrm)
    const int bid = blockIdx.x;
    const int tid = threadIdx.x;
    if (bid < 1056) {
        int ihp = bid % 66, b = bid / 66;
        transform_body(ihp, b, tid, x, xt, (float*)smem);
    } else {
        int sb = bid - 1056;
        int chunk = sb & 31, cog = (sb >> 5) & 3, b = sb >> 7;
        synth_body(chunk, cog, b, tid, weight, tb, tq, tn, tx,
                   mb, mq, mn, mx, feat, aws, (short*)smem);
    }
}

// Standalone synth (gather-fallback path only).
__global__ __launch_bounds__(256) void synth_aws(
    const float* __restrict__ weight,
    const float* __restrict__ tb, const float* __restrict__ tq,
    const float* __restrict__ tn, const float* __restrict__ tx,
    const float* __restrict__ mb, const float* __restrict__ mq,
    const float* __restrict__ mn, const float* __restrict__ mx,
    const float* __restrict__ feat,
    short* __restrict__ aws)
{
    __shared__ __align__(16) short lbuf[4][32][AST];
    const int chunk = blockIdx.x, cog = blockIdx.y, b = blockIdx.z;
    synth_body(chunk, cog, b, threadIdx.x, weight, tb, tq, tn, tx,
               mb, mq, mn, mx, feat, aws, &lbuf[0][0][0]);
}

// ---------------------------------------------------------------------------
// Kernel C: MFMA deconv, async global_load_lds double-buffer.
// 1D grid 2048 with bijective XCD swizzle: each XCD gets a contiguous 256-block
// chunk = 2 full b's (aws+xt working set ~3.7MB/b, near-L2-fit), so the 32
// nt-blocks sharing one (b,cls) aws slice hit the same L2 instead of 8 L2s.
// ---------------------------------------------------------------------------
__global__ __launch_bounds__(256) void deconv_mfma2(
    const short* __restrict__ aws, const short* __restrict__ xt,
    const float* __restrict__ bias, const float* __restrict__ prelu_a,
    float* __restrict__ out)
{
    const int tid  = threadIdx.x;
    const int lane = tid & 63;
    const int wv   = tid >> 6;
    const int wm   = wv & 1, wn = wv >> 1;
    const int o    = blockIdx.x;              // 0..2047
    const int n    = (o & 7) * 256 + (o >> 3);  // XCD-contiguous remap
    const int nt   = n & 31;
    const int cls  = (n >> 5) & 3;
    const int b    = n >> 7;
    const int a0 = (nt >> 2) * 8, c0 = (nt & 3) * 16;
    const int r = cls >> 1, s = cls & 1;

    __shared__ __align__(16) short als[2][ACHUNK];  // A: [co(128)][AST]
    __shared__ __align__(16) short xsb[2][1536];    // B: [row9][col17][ci8]+pad

    // ---- staging plan: transfer t = wv + i*4; t<11 -> A (11KB), 11..13 -> B ----
    const short* gb[4]; int gstep[4], loff[4], isB[4], act[4];
    {
        const size_t awb = (((size_t)b*4 + cls)*32) * ACHUNK;
        #pragma unroll
        for (int i = 0; i < 4; ++i) {
            int t = wv + i*4;
            act[i] = (t < 14);
            if (t < 11) {
                gb[i]    = aws + awb + t*512 + lane*8;
                gstep[i] = ACHUNK;  loff[i] = t*512;  isB[i] = 0;
            } else {
                int j = t - 11;                     // 0..2 (garbage if !act)
                int p = j*64 + lane; if (p > 152) p = 152;
                int row = p / 17, col = p - row*17;
                gb[i] = xt + (((size_t)b*32*66 + (a0 + r + row))*66
                              + (c0 + s + col)) * 8;
                gstep[i] = 66*66*8;  loff[i] = j*512;  isB[i] = 1;
            }
        }
    }

    f32x4 acc[4][4];
    #pragma unroll
    for (int mi = 0; mi < 4; ++mi)
        #pragma unroll
        for (int ni = 0; ni < 4; ++ni)
            acc[mi][ni] = (f32x4){0.f, 0.f, 0.f, 0.f};

    const int nlo = lane & 15;
    const int q   = lane >> 4;
    const int dh  = q >> 1, dw = q & 1;

    // stage chunk 0 into buffer 0
    #pragma unroll
    for (int i = 0; i < 4; ++i)
        if (act[i])
            async_ld16(gb[i], isB[i] ? &xsb[0][loff[i]] : &als[0][loff[i]]);

    for (int c = 0; c < 32; ++c) {
        __syncthreads();                 // drains vmcnt -> buf[c&1] ready
        const int sel = c & 1;
        if (c < 31) {                    // prefetch next chunk into other buf
            const int ps = sel ^ 1;
            #pragma unroll
            for (int i = 0; i < 4; ++i)
                if (act[i])
                    async_ld16(gb[i] + (size_t)(c+1)*gstep[i],
                               isB[i] ? &xsb[ps][loff[i]] : &als[ps][loff[i]]);
        }
        bf16x8 af[4], bfr[4];
        #pragma unroll
        for (int mi = 0; mi < 4; ++mi)
            af[mi] = *(const bf16x8*)(&als[sel][(wm*64 + mi*16 + nlo)*AST + q*8]);
        #pragma unroll
        for (int ni = 0; ni < 4; ++ni) {
            int a_local = wn*4 + ni;
            bfr[ni] = *(const bf16x8*)(&xsb[sel][((a_local + dh)*17 + (nlo + dw))*8]);
        }
        #pragma unroll
        for (int mi = 0; mi < 4; ++mi)
            #pragma unroll
            for (int ni = 0; ni < 4; ++ni)
                acc[mi][ni] = __builtin_amdgcn_mfma_f32_16x16x32_bf16(
                    af[mi], bfr[ni], acc[mi][ni], 0, 0, 0);
    }

    // ---- epilogue: bias + PReLU ----
    const float pa = prelu_a[0];
    #pragma unroll
    for (int mi = 0; mi < 4; ++mi) {
        #pragma unroll
        for (int reg = 0; reg < 4; ++reg) {
            int co = wm*64 + mi*16 + q*4 + reg;
            float bv = bias[co];
            #pragma unroll
            for (int ni = 0; ni < 4; ++ni) {
                int a_local = wn*4 + ni;
                int oh = 2*(a0 + a_local) + r;
                int ow = 2*(c0 + nlo) + s;
                float v = acc[mi][ni][reg] + bv;
                v = (v >= 0.f) ? v : pa*v;
                out[(((size_t)b*COUT_ + co)*OH_ + oh)*OW_ + ow] = v;
            }
        }
    }
}

// ---------------------------------------------------------------------------
// Middle fallback: gather-based MFMA deconv (needs only aws in ws).
// ---------------------------------------------------------------------------
__global__ __launch_bounds__(256, 2) void deconv_mfma_gather(
    const float* __restrict__ x,
    const short* __restrict__ aws,
    const float* __restrict__ bias,
    const float* __restrict__ prelu_a,
    float* __restrict__ out)
{
    const int tid  = threadIdx.x;
    const int lane = tid & 63;
    const int wv   = tid >> 6;
    const int wm   = wv & 1, wn = wv >> 1;
    const int nt   = blockIdx.x;
    const int cls  = blockIdx.y;
    const int b    = blockIdx.z;
    const int a0 = (nt >> 2) * 8, c0 = (nt & 3) * 16;
    const int r = cls >> 1, s = cls & 1;

    __shared__ __align__(16) short xs[1280];
    __shared__ __align__(16) short als[ACHUNK];

    int goff[5], gstep[5], gok[5];
    #pragma unroll
    for (int i = 0; i < 5; ++i) {
        int e    = tid + i*256;
        int ci_l = e & 7;
        int rc   = e >> 3;
        int row  = rc / 17;
        int col  = rc - row*17;
        int ih   = a0 - 1 + r + row;
        int iw   = c0 - 1 + s + col;
        int ok   = (rc < 153) && ((unsigned)ih < (unsigned)H_)
                              && ((unsigned)iw < (unsigned)W_);
        goff[i]  = ok ? (((b*CIN_ + ci_l)*H_ + ih)*W_ + iw) : 0;
        gstep[i] = ok ? (8*H_*W_) : 0;
        gok[i]   = ok;
    }
    const size_t aws_base = (((size_t)b*4 + cls)*32) * ACHUNK;

    f32x4 acc[4][4];
    #pragma unroll
    for (int mi = 0; mi < 4; ++mi)
        #pragma unroll
        for (int ni = 0; ni < 4; ++ni)
            acc[mi][ni] = (f32x4){0.f, 0.f, 0.f, 0.f};

    const int nlo = lane & 15;
    const int q   = lane >> 4;
    const int dh  = q >> 1, dw = q & 1;

    for (int chunk = 0; chunk < 32; ++chunk) {
        __syncthreads();
        #pragma unroll
        for (int i = 0; i < 5; ++i) {
            float v = x[goff[i] + chunk*gstep[i]];
            v = gok[i] ? v : 0.0f;
            xs[tid + i*256] = f2bf(v);
        }
        {
            const short* src = aws + aws_base + (size_t)chunk*ACHUNK;
            #pragma unroll
            for (int i = 0; i < 3; ++i) {
                int idx = wv + i*4;
                if (idx < 11)
                    async_ld16(src + idx*512 + lane*8, als + idx*512);
            }
        }
        __syncthreads();
        bf16x8 af[4], bfr[4];
        #pragma unroll
        for (int mi = 0; mi < 4; ++mi)
            af[mi] = *(const bf16x8*)(als + (wm*64 + mi*16 + nlo)*AST + q*8);
        #pragma unroll
        for (int ni = 0; ni < 4; ++ni) {
            int a_local = wn*4 + ni;
            bfr[ni] = *(const bf16x8*)(xs + ((a_local + dh)*17 + (nlo + dw))*8);
        }
        #pragma unroll
        for (int mi = 0; mi < 4; ++mi)
            #pragma unroll
            for (int ni = 0; ni < 4; ++ni)
                acc[mi][ni] = __builtin_amdgcn_mfma_f32_16x16x32_bf16(
                    af[mi], bfr[ni], acc[mi][ni], 0, 0, 0);
    }

    const float pa = prelu_a[0];
    #pragma unroll
    for (int mi = 0; mi < 4; ++mi) {
        #pragma unroll
        for (int reg = 0; reg < 4; ++reg) {
            int co = wm*64 + mi*16 + q*4 + reg;
            float bv = bias[co];
            #pragma unroll
            for (int ni = 0; ni < 4; ++ni) {
                int a_local = wn*4 + ni;
                int oh = 2*(a0 + a_local) + r;
                int ow = 2*(c0 + nlo) + s;
                float v = acc[mi][ni][reg] + bv;
                v = (v >= 0.f) ? v : pa*v;
                out[(((size_t)b*COUT_ + co)*OH_ + oh)*OW_ + ow] = v;
            }
        }
    }
}

// ---------------------------------------------------------------------------
// Last-resort fallback: fp32 direct kernel, in-kernel weight synthesis, no ws.
// ---------------------------------------------------------------------------
__global__ __launch_bounds__(256) void deconv_fallback(
    const float* __restrict__ x,
    const float* __restrict__ weight,
    const float* __restrict__ tb, const float* __restrict__ tq,
    const float* __restrict__ tn, const float* __restrict__ tx,
    const float* __restrict__ mb, const float* __restrict__ mq,
    const float* __restrict__ mn, const float* __restrict__ mx,
    const float* __restrict__ feat,
    const float* __restrict__ bias, const float* __restrict__ prelu_a,
    float* __restrict__ out)
{
    const int tid    = threadIdx.x;
    const int tile   = blockIdx.x;
    const int coT    = blockIdx.y;
    const int b      = blockIdx.z;
    const int tile_h = tile >> 3, tile_w = tile & 7;
    const int a0 = tile_h * 8;
    const int c0 = tile_w * 8;
    const int co0 = coT * 64;

    const int tco = tid & 15;
    const int tpx = tid >> 4;
    const int rr  = tpx >> 2, rc = tpx & 3;

    __shared__ float xsf[4][100];
    __shared__ float wsh[4][16][64];

    float acc[4][4][4];
    #pragma unroll
    for (int i = 0; i < 4; ++i)
        #pragma unroll
        for (int j = 0; j < 4; ++j)
            #pragma unroll
            for (int c = 0; c < 4; ++c) acc[i][j][c] = 0.f;

    float f0 = feat[b*4 + 0], f1 = feat[b*4 + 1];
    float f2 = feat[b*4 + 2], f3 = feat[b*4 + 3];

    for (int chunk = 0; chunk < CIN_ / 4; ++chunk) {
        const int ci0 = chunk * 4;
        __syncthreads();
        for (int e = tid; e < 400; e += 256) {
            int ci_l = e / 100; int rem = e - ci_l * 100;
            int rI = rem / 10;  int cI = rem - rI * 10;
            int ih = a0 - 1 + rI, iw = c0 - 1 + cI;
            float v = 0.f;
            if ((unsigned)ih < (unsigned)H_ && (unsigned)iw < (unsigned)W_)
                v = x[(((size_t)b * CIN_ + ci0 + ci_l) * H_ + ih) * W_ + iw];
            xsf[ci_l][rem] = v;
        }
        #pragma unroll
        for (int k = 0; k < 4; ++k) {
            int g = tid + k * 256;
            int ci_l = g >> 8; int rrem = g & 255;
            int co_l = rrem >> 2; int tg = (rrem & 3) * 4;
            int cico = (ci0 + ci_l) * COUT_ + co0 + co_l;
            int e = cico * 16 + tg;
            float4 w  = *(const float4*)(weight + e);
            float4 vb = *(const float4*)(tb + e);
            float4 vq = *(const float4*)(tq + e);
            float4 vn = *(const float4*)(tn + e);
            float4 vx = *(const float4*)(tx + e);
            float sb = mb[cico] * f0, sq = mq[cico] * f1;
            float sn = mn[cico] * f2, sx = mx[cico] * f3;
            float4 wvv;
            wvv.x = w.x + sb*vb.x + sq*vq.x + sn*vn.x + sx*vx.x;
            wvv.y = w.y + sb*vb.y + sq*vq.y + sn*vn.y + sx*vx.y;
            wvv.z = w.z + sb*vb.z + sq*vq.z + sn*vn.z + sx*vx.z;
            wvv.w = w.w + sb*vb.w + sq*vq.w + sn*vn.w + sx*vx.w;
            wsh[ci_l][tg + 0][co_l] = wvv.x;
            wsh[ci_l][tg + 1][co_l] = wvv.y;
            wsh[ci_l][tg + 2][co_l] = wvv.z;
            wsh[ci_l][tg + 3][co_l] = wvv.w;
        }
        __syncthreads();
        #pragma unroll
        for (int ci_l = 0; ci_l < 4; ++ci_l) {
            float xpv[4][4];
            #pragma unroll
            for (int i = 0; i < 4; ++i)
                #pragma unroll
                for (int j = 0; j < 4; ++j)
                    xpv[i][j] = xsf[ci_l][(rr*2 + i) * 10 + rc*2 + j];
            #pragma unroll
            for (int kh = 0; kh < 4; ++kh) {
                const int rpar = (kh & 1) ? 0 : 1;
                const int offh = (kh == 0) ? 2 : (kh == 3) ? 0 : 1;
                #pragma unroll
                for (int kw = 0; kw < 4; ++kw) {
                    const int spar = (kw & 1) ? 0 : 1;
                    const int offw = (kw == 0) ? 2 : (kw == 3) ? 0 : 1;
                    float4 wvv = *(const float4*)&wsh[ci_l][kh*4 + kw][tco*4];
                    float wr[4] = {wvv.x, wvv.y, wvv.z, wvv.w};
                    #pragma unroll
                    for (int da = 0; da < 2; ++da)
                        #pragma unroll
                        for (int dc = 0; dc < 2; ++dc) {
                            const float xvv = xpv[da + offh][dc + offw];
                            #pragma unroll
                            for (int cc = 0; cc < 4; ++cc)
                                acc[2*da + rpar][2*dc + spar][cc] =
                                    fmaf(wr[cc], xvv, acc[2*da + rpar][2*dc + spar][cc]);
                        }
                }
            }
        }
    }
    const float pa  = prelu_a[0];
    const int oh0 = tile_h * 16 + rr * 4;
    const int ow0 = tile_w * 16 + rc * 4;
    #pragma unroll
    for (int cc = 0; cc < 4; ++cc) {
        const int co = co0 + tco * 4 + cc;
        const float bv = bias[co];
        #pragma unroll
        for (int dr = 0; dr < 4; ++dr)
            #pragma unroll
            for (int dw2 = 0; dw2 < 4; ++dw2) {
                float v = acc[dr][dw2][cc] + bv;
                v = (v >= 0.f) ? v : pa * v;
                out[(((size_t)b * COUT_ + co) * OH_ + (oh0 + dr)) * OW_ + (ow0 + dw2)] = v;
            }
    }
}

extern "C" void kernel_launch(void* const* d_in, const int* in_sizes, int n_in,
                              void* d_out, int out_size, void* d_ws, size_t ws_size,
                              hipStream_t stream) {
    (void)in_sizes; (void)n_in; (void)out_size;
    const float* x      = (const float*)d_in[0];
    const float* feat   = (const float*)d_in[1];
    const float* weight = (const float*)d_in[2];
    const float* tb     = (const float*)d_in[3];
    const float* tq     = (const float*)d_in[4];
    const float* tn     = (const float*)d_in[5];
    const float* tx     = (const float*)d_in[6];
    const float* mb     = (const float*)d_in[7];
    const float* mq     = (const float*)d_in[8];
    const float* mn     = (const float*)d_in[9];
    const float* mx     = (const float*)d_in[10];
    const float* bias   = (const float*)d_in[11];
    const float* prelu  = (const float*)d_in[12];
    float* out = (float*)d_out;

    const size_t aws_sz = (size_t)B_ * 4 * 32 * 128 * AST * sizeof(short);  // 23.07 MB
    const size_t xt_sz  = (size_t)B_ * 32 * 66 * 66 * 8 * sizeof(short);    // 35.68 MB

    if (ws_size >= aws_sz + xt_sz) {
        short* aws = (short*)d_ws;
        short* xt  = (short*)((char*)d_ws + aws_sz);
        prep_fused<<<dim3(1056 + 2048), 256, 0, stream>>>(
            x, weight, tb, tq, tn, tx, mb, mq, mn, mx, feat, aws, xt);
        deconv_mfma2<<<dim3(2048), 256, 0, stream>>>(
            aws, xt, bias, prelu, out);
    } else if (ws_size >= aws_sz) {
        short* aws = (short*)d_ws;
        synth_aws<<<dim3(32, 4, 16), 256, 0, stream>>>(
            weight, tb, tq, tn, tx, mb, mq, mn, mx, feat, aws);
        deconv_mfma_gather<<<dim3(32, 4, 16), 256, 0, stream>>>(
            x, aws, bias, prelu, out);
    } else {
        deconv_fallback<<<dim3(64, 2, 16), 256, 0, stream>>>(
            x, weight, tb, tq, tn, tx, mb, mq, mn, mx, feat, bias, prelu, out);
    }
}

// Round 3
// 285.807 us; speedup vs baseline: 1.1232x; 1.1232x over previous
//
#include <hip/hip_runtime.h>
#include <hip/hip_bf16.h>
#include <cstddef>
#include <cstdint>

#define B_    16
#define CIN_  256
#define COUT_ 128
#define H_    64
#define W_    64
#define OH_   128
#define OW_   128

// A-matrix row stride in shorts: 32 real k-values + 12 pad (bank-conflict fix;
// round-1 measured SQ_LDS_BANK_CONFLICT 4.19M -> 0 with AST=44).
#define AST   44
#define ACHUNK (128*AST)          // shorts per (cls,chunk) A slice = 5632

typedef __attribute__((ext_vector_type(8))) short bf16x8;
typedef __attribute__((ext_vector_type(4))) float f32x4;

__device__ inline short f2bf(float f) {
    __hip_bfloat16 h = __float2bfloat16(f);
    return *reinterpret_cast<short*>(&h);
}

__device__ inline void async_ld16(const void* g, void* l) {
    typedef const __attribute__((address_space(1))) unsigned int* gp_t;
    typedef __attribute__((address_space(3))) unsigned int* lp_t;
    __builtin_amdgcn_global_load_lds((gp_t)g, (lp_t)l, 16, 0, 0);
}

// ---------------------------------------------------------------------------
// Synth body v3: weights are b-invariant -> load once into REGISTERS, loop b.
// Block = (chunk, cog8): 8 ci x 8 co x 16 k slice. Thread (ci_l,co_l,kh) owns
// 4 kw elements of 5 tensors in regs; per b: compute, stage in 2KB LDS,
// coalesced copy-out. Read traffic: 200MB (per-b re-read) -> 12.5MB total.
// ---------------------------------------------------------------------------
__device__ inline void synth_body(
    int chunk, int cog8, int tid,
    const float* __restrict__ weight,
    const float* __restrict__ tb, const float* __restrict__ tq,
    const float* __restrict__ tn, const float* __restrict__ tx,
    const float* __restrict__ mb, const float* __restrict__ mq,
    const float* __restrict__ mn, const float* __restrict__ mx,
    const float* __restrict__ feat,
    short* __restrict__ aws,
    short* lbuf /* [4 cls][8 co][32 k] shorts = 2KB, 16B aligned */)
{
    const int ci_l = tid >> 5;          // 0..7
    const int co_l = (tid >> 2) & 7;    // 0..7
    const int kh   = tid & 3;           // 0..3
    const int base = (chunk*8 + ci_l) * COUT_ + cog8*8 + co_l;

    const float4 w4 = *(const float4*)(weight + (size_t)base*16 + kh*4);
    const float4 b4 = *(const float4*)(tb + (size_t)base*16 + kh*4);
    const float4 q4 = *(const float4*)(tq + (size_t)base*16 + kh*4);
    const float4 n4 = *(const float4*)(tn + (size_t)base*16 + kh*4);
    const float4 x4 = *(const float4*)(tx + (size_t)base*16 + kh*4);
    const float m_b = mb[base], m_q = mq[base];
    const float m_n = mn[base], m_x = mx[base];
    const float* wp = (const float*)&w4;
    const float* bp = (const float*)&b4;
    const float* qp = (const float*)&q4;
    const float* np = (const float*)&n4;
    const float* xp = (const float*)&x4;

    const int r  = (kh+1)&1;
    const int dh = (kh<2) ? 1 : 0;

    for (int b = 0; b < 16; ++b) {
        const float sb = m_b * feat[b*4+0];
        const float sq = m_q * feat[b*4+1];
        const float sn = m_n * feat[b*4+2];
        const float sx = m_x * feat[b*4+3];
        #pragma unroll
        for (int kw = 0; kw < 4; ++kw) {
            int s  = (kw+1)&1;
            int dw = (kw<2) ? 1 : 0;
            float v = wp[kw] + sb*bp[kw] + sq*qp[kw] + sn*np[kw] + sx*xp[kw];
            lbuf[((r*2+s)*8 + co_l)*32 + (dh*2+dw)*8 + ci_l] = f2bf(v);
        }
        __syncthreads();
        if (tid < 128) {                 // 128 x int4 = 2KB copy-out
            int cls  = tid >> 5;
            int j    = tid & 31;         // int4 index within cls slice
            int co_r = j >> 2, t4 = j & 3;
            size_t dst = ((((size_t)(b*4 + cls)*32 + chunk)*128)
                          + cog8*8 + co_r) * AST + t4*8;
            *(int4*)(aws + dst) = *(const int4*)(lbuf + (cls*8 + co_r)*32 + t4*8);
        }
        __syncthreads();
    }
}

// ---------------------------------------------------------------------------
// Transform body: x (fp32 NCHW) -> x_t bf16 [b][chunk32][ihp66][iwp66][ci8]
// with zero halo. float4 x-loads + padded [128][68] LDS transpose.
// ---------------------------------------------------------------------------
__device__ inline void transform_body(
    int ihp, int b, int tid,
    const float* __restrict__ x, short* __restrict__ xt,
    float* xls /* [128][68] floats */)
{
    const int4 z4 = {0, 0, 0, 0};

    if (ihp == 0 || ihp == 65) {       // border rows: zero all chunks/cols
        for (int j = tid; j < 2112; j += 256) {       // 32 chunks * 66 cols
            int c = j / 66, iwp = j - c*66;
            *(int4*)(xt + ((((size_t)b*32 + c)*66 + ihp)*66 + iwp)*8) = z4;
        }
        return;
    }
    if (tid < 64) {                    // border cols iwp in {0,65}
        int c = tid >> 1, iwp = (tid & 1) * 65;
        *(int4*)(xt + ((((size_t)b*32 + c)*66 + ihp)*66 + iwp)*8) = z4;
    }
    const int ih = ihp - 1;
    for (int half = 0; half < 2; ++half) {
        __syncthreads();
        #pragma unroll
        for (int it = 0; it < 8; ++it) {
            int ci_l = it*16 + (tid >> 4);
            int iw4  = (tid & 15) * 4;
            float4 v = *(const float4*)(
                x + (((size_t)b*256 + half*128 + ci_l)*64 + ih)*64 + iw4);
            *(float4*)(xls + ci_l*68 + iw4) = v;
        }
        __syncthreads();
        #pragma unroll
        for (int it2 = 0; it2 < 4; ++it2) {
            int chunk_l = it2*4 + (tid >> 6);
            int chunk   = half*16 + chunk_l;
            int iw      = tid & 63;
            short s8[8];
            #pragma unroll
            for (int j = 0; j < 8; ++j)
                s8[j] = f2bf(xls[(chunk_l*8 + j)*68 + iw]);
            *(int4*)(xt + ((((size_t)b*32 + chunk)*66 + ihp)*66 + (iw+1))*8)
                = *(const int4*)s8;
        }
    }
}

// ---------------------------------------------------------------------------
// Fused prep: transform blocks [0,1056) + synth blocks [1056,1568).
// ---------------------------------------------------------------------------
__global__ __launch_bounds__(256) void prep_fused(
    const float* __restrict__ x,
    const float* __restrict__ weight,
    const float* __restrict__ tb, const float* __restrict__ tq,
    const float* __restrict__ tn, const float* __restrict__ tx,
    const float* __restrict__ mb, const float* __restrict__ mq,
    const float* __restrict__ mn, const float* __restrict__ mx,
    const float* __restrict__ feat,
    short* __restrict__ aws, short* __restrict__ xt)
{
    __shared__ __align__(16) char smem[34816];   // max(2048 synth, 34816 xfrm)
    const int bid = blockIdx.x;
    const int tid = threadIdx.x;
    if (bid < 1056) {
        int ihp = bid % 66, b = bid / 66;
        transform_body(ihp, b, tid, x, xt, (float*)smem);
    } else {
        int sb = bid - 1056;             // 0..511
        int chunk = sb & 31, cog8 = sb >> 5;
        synth_body(chunk, cog8, tid, weight, tb, tq, tn, tx,
                   mb, mq, mn, mx, feat, aws, (short*)smem);
    }
}

// Standalone synth (gather-fallback path only). grid (32, 16).
__global__ __launch_bounds__(256) void synth_aws(
    const float* __restrict__ weight,
    const float* __restrict__ tb, const float* __restrict__ tq,
    const float* __restrict__ tn, const float* __restrict__ tx,
    const float* __restrict__ mb, const float* __restrict__ mq,
    const float* __restrict__ mn, const float* __restrict__ mx,
    const float* __restrict__ feat,
    short* __restrict__ aws)
{
    __shared__ __align__(16) short lbuf[4][8][32];
    synth_body(blockIdx.x, blockIdx.y, threadIdx.x, weight, tb, tq, tn, tx,
               mb, mq, mn, mx, feat, aws, &lbuf[0][0][0]);
}

// ---------------------------------------------------------------------------
// Kernel C: MFMA deconv, async global_load_lds double-buffer.
// 1D grid 2048, bijective XCD decode: x=o&7 (XCD), l=o>>3 (slot).
//   cls = l&3 (FASTEST: write-partner blocks cls 0/1 and 2/3 are adjacent in
//   dispatch on the same XCD -> their half-line epilogue stores land in L2
//   within ~1 block-slot of each other -> merge into full-line writebacks;
//   round-1's 32-slot separation lost the merge, WRITE_SIZE 140->260MB),
//   nt = (l>>2)&31, b = 2*x + (l>>7) (b-pair per XCD keeps FETCH ~44MB).
// ---------------------------------------------------------------------------
__global__ __launch_bounds__(256) void deconv_mfma2(
    const short* __restrict__ aws, const short* __restrict__ xt,
    const float* __restrict__ bias, const float* __restrict__ prelu_a,
    float* __restrict__ out)
{
    const int tid  = threadIdx.x;
    const int lane = tid & 63;
    const int wv   = tid >> 6;
    const int wm   = wv & 1, wn = wv >> 1;
    const int o    = blockIdx.x;              // 0..2047
    const int x8   = o & 7;
    const int l    = o >> 3;                  // 0..255
    const int cls  = l & 3;
    const int nt   = (l >> 2) & 31;
    const int b    = 2*x8 + (l >> 7);
    const int a0 = (nt >> 2) * 8, c0 = (nt & 3) * 16;
    const int r = cls >> 1, s = cls & 1;

    __shared__ __align__(16) short als[2][ACHUNK];  // A: [co(128)][AST]
    __shared__ __align__(16) short xsb[2][1536];    // B: [row9][col17][ci8]+pad

    // ---- staging plan: transfer t = wv + i*4; t<11 -> A (11KB), 11..13 -> B ----
    const short* gb[4]; int gstep[4], loff[4], isB[4], act[4];
    {
        const size_t awb = (((size_t)b*4 + cls)*32) * ACHUNK;
        #pragma unroll
        for (int i = 0; i < 4; ++i) {
            int t = wv + i*4;
            act[i] = (t < 14);
            if (t < 11) {
                gb[i]    = aws + awb + t*512 + lane*8;
                gstep[i] = ACHUNK;  loff[i] = t*512;  isB[i] = 0;
            } else {
                int j = t - 11;                     // 0..2 (garbage if !act)
                int p = j*64 + lane; if (p > 152) p = 152;
                int row = p / 17, col = p - row*17;
                gb[i] = xt + (((size_t)b*32*66 + (a0 + r + row))*66
                              + (c0 + s + col)) * 8;
                gstep[i] = 66*66*8;  loff[i] = j*512;  isB[i] = 1;
            }
        }
    }

    f32x4 acc[4][4];
    #pragma unroll
    for (int mi = 0; mi < 4; ++mi)
        #pragma unroll
        for (int ni = 0; ni < 4; ++ni)
            acc[mi][ni] = (f32x4){0.f, 0.f, 0.f, 0.f};

    const int nlo = lane & 15;
    const int q   = lane >> 4;
    const int dh  = q >> 1, dw = q & 1;

    // stage chunk 0 into buffer 0
    #pragma unroll
    for (int i = 0; i < 4; ++i)
        if (act[i])
            async_ld16(gb[i], isB[i] ? &xsb[0][loff[i]] : &als[0][loff[i]]);

    for (int c = 0; c < 32; ++c) {
        __syncthreads();                 // drains vmcnt -> buf[c&1] ready
        const int sel = c & 1;
        if (c < 31) {                    // prefetch next chunk into other buf
            const int ps = sel ^ 1;
            #pragma unroll
            for (int i = 0; i < 4; ++i)
                if (act[i])
                    async_ld16(gb[i] + (size_t)(c+1)*gstep[i],
                               isB[i] ? &xsb[ps][loff[i]] : &als[ps][loff[i]]);
        }
        bf16x8 af[4], bfr[4];
        #pragma unroll
        for (int mi = 0; mi < 4; ++mi)
            af[mi] = *(const bf16x8*)(&als[sel][(wm*64 + mi*16 + nlo)*AST + q*8]);
        #pragma unroll
        for (int ni = 0; ni < 4; ++ni) {
            int a_local = wn*4 + ni;
            bfr[ni] = *(const bf16x8*)(&xsb[sel][((a_local + dh)*17 + (nlo + dw))*8]);
        }
        #pragma unroll
        for (int mi = 0; mi < 4; ++mi)
            #pragma unroll
            for (int ni = 0; ni < 4; ++ni)
                acc[mi][ni] = __builtin_amdgcn_mfma_f32_16x16x32_bf16(
                    af[mi], bfr[ni], acc[mi][ni], 0, 0, 0);
    }

    // ---- epilogue: bias + PReLU ----
    const float pa = prelu_a[0];
    #pragma unroll
    for (int mi = 0; mi < 4; ++mi) {
        #pragma unroll
        for (int reg = 0; reg < 4; ++reg) {
            int co = wm*64 + mi*16 + q*4 + reg;
            float bv = bias[co];
            #pragma unroll
            for (int ni = 0; ni < 4; ++ni) {
                int a_local = wn*4 + ni;
                int oh = 2*(a0 + a_local) + r;
                int ow = 2*(c0 + nlo) + s;
                float v = acc[mi][ni][reg] + bv;
                v = (v >= 0.f) ? v : pa*v;
                out[(((size_t)b*COUT_ + co)*OH_ + oh)*OW_ + ow] = v;
            }
        }
    }
}

// ---------------------------------------------------------------------------
// Middle fallback: gather-based MFMA deconv (needs only aws in ws).
// ---------------------------------------------------------------------------
__global__ __launch_bounds__(256, 2) void deconv_mfma_gather(
    const float* __restrict__ x,
    const short* __restrict__ aws,
    const float* __restrict__ bias,
    const float* __restrict__ prelu_a,
    float* __restrict__ out)
{
    const int tid  = threadIdx.x;
    const int lane = tid & 63;
    const int wv   = tid >> 6;
    const int wm   = wv & 1, wn = wv >> 1;
    const int nt   = blockIdx.x;
    const int cls  = blockIdx.y;
    const int b    = blockIdx.z;
    const int a0 = (nt >> 2) * 8, c0 = (nt & 3) * 16;
    const int r = cls >> 1, s = cls & 1;

    __shared__ __align__(16) short xs[1280];
    __shared__ __align__(16) short als[ACHUNK];

    int goff[5], gstep[5], gok[5];
    #pragma unroll
    for (int i = 0; i < 5; ++i) {
        int e    = tid + i*256;
        int ci_l = e & 7;
        int rc   = e >> 3;
        int row  = rc / 17;
        int col  = rc - row*17;
        int ih   = a0 - 1 + r + row;
        int iw   = c0 - 1 + s + col;
        int ok   = (rc < 153) && ((unsigned)ih < (unsigned)H_)
                              && ((unsigned)iw < (unsigned)W_);
        goff[i]  = ok ? (((b*CIN_ + ci_l)*H_ + ih)*W_ + iw) : 0;
        gstep[i] = ok ? (8*H_*W_) : 0;
        gok[i]   = ok;
    }
    const size_t aws_base = (((size_t)b*4 + cls)*32) * ACHUNK;

    f32x4 acc[4][4];
    #pragma unroll
    for (int mi = 0; mi < 4; ++mi)
        #pragma unroll
        for (int ni = 0; ni < 4; ++ni)
            acc[mi][ni] = (f32x4){0.f, 0.f, 0.f, 0.f};

    const int nlo = lane & 15;
    const int q   = lane >> 4;
    const int dh  = q >> 1, dw = q & 1;

    for (int chunk = 0; chunk < 32; ++chunk) {
        __syncthreads();
        #pragma unroll
        for (int i = 0; i < 5; ++i) {
            float v = x[goff[i] + chunk*gstep[i]];
            v = gok[i] ? v : 0.0f;
            xs[tid + i*256] = f2bf(v);
        }
        {
            const short* src = aws + aws_base + (size_t)chunk*ACHUNK;
            #pragma unroll
            for (int i = 0; i < 3; ++i) {
                int idx = wv + i*4;
                if (idx < 11)
                    async_ld16(src + idx*512 + lane*8, als + idx*512);
            }
        }
        __syncthreads();
        bf16x8 af[4], bfr[4];
        #pragma unroll
        for (int mi = 0; mi < 4; ++mi)
            af[mi] = *(const bf16x8*)(als + (wm*64 + mi*16 + nlo)*AST + q*8);
        #pragma unroll
        for (int ni = 0; ni < 4; ++ni) {
            int a_local = wn*4 + ni;
            bfr[ni] = *(const bf16x8*)(xs + ((a_local + dh)*17 + (nlo + dw))*8);
        }
        #pragma unroll
        for (int mi = 0; mi < 4; ++mi)
            #pragma unroll
            for (int ni = 0; ni < 4; ++ni)
                acc[mi][ni] = __builtin_amdgcn_mfma_f32_16x16x32_bf16(
                    af[mi], bfr[ni], acc[mi][ni], 0, 0, 0);
    }

    const float pa = prelu_a[0];
    #pragma unroll
    for (int mi = 0; mi < 4; ++mi) {
        #pragma unroll
        for (int reg = 0; reg < 4; ++reg) {
            int co = wm*64 + mi*16 + q*4 + reg;
            float bv = bias[co];
            #pragma unroll
            for (int ni = 0; ni < 4; ++ni) {
                int a_local = wn*4 + ni;
                int oh = 2*(a0 + a_local) + r;
                int ow = 2*(c0 + nlo) + s;
                float v = acc[mi][ni][reg] + bv;
                v = (v >= 0.f) ? v : pa*v;
                out[(((size_t)b*COUT_ + co)*OH_ + oh)*OW_ + ow] = v;
            }
        }
    }
}

// ---------------------------------------------------------------------------
// Last-resort fallback: fp32 direct kernel, in-kernel weight synthesis, no ws.
// ---------------------------------------------------------------------------
__global__ __launch_bounds__(256) void deconv_fallback(
    const float* __restrict__ x,
    const float* __restrict__ weight,
    const float* __restrict__ tb, const float* __restrict__ tq,
    const float* __restrict__ tn, const float* __restrict__ tx,
    const float* __restrict__ mb, const float* __restrict__ mq,
    const float* __restrict__ mn, const float* __restrict__ mx,
    const float* __restrict__ feat,
    const float* __restrict__ bias, const float* __restrict__ prelu_a,
    float* __restrict__ out)
{
    const int tid    = threadIdx.x;
    const int tile   = blockIdx.x;
    const int coT    = blockIdx.y;
    const int b      = blockIdx.z;
    const int tile_h = tile >> 3, tile_w = tile & 7;
    const int a0 = tile_h * 8;
    const int c0 = tile_w * 8;
    const int co0 = coT * 64;

    const int tco = tid & 15;
    const int tpx = tid >> 4;
    const int rr  = tpx >> 2, rc = tpx & 3;

    __shared__ float xsf[4][100];
    __shared__ float wsh[4][16][64];

    float acc[4][4][4];
    #pragma unroll
    for (int i = 0; i < 4; ++i)
        #pragma unroll
        for (int j = 0; j < 4; ++j)
            #pragma unroll
            for (int c = 0; c < 4; ++c) acc[i][j][c] = 0.f;

    float f0 = feat[b*4 + 0], f1 = feat[b*4 + 1];
    float f2 = feat[b*4 + 2], f3 = feat[b*4 + 3];

    for (int chunk = 0; chunk < CIN_ / 4; ++chunk) {
        const int ci0 = chunk * 4;
        __syncthreads();
        for (int e = tid; e < 400; e += 256) {
            int ci_l = e / 100; int rem = e - ci_l * 100;
            int rI = rem / 10;  int cI = rem - rI * 10;
            int ih = a0 - 1 + rI, iw = c0 - 1 + cI;
            float v = 0.f;
            if ((unsigned)ih < (unsigned)H_ && (unsigned)iw < (unsigned)W_)
                v = x[(((size_t)b * CIN_ + ci0 + ci_l) * H_ + ih) * W_ + iw];
            xsf[ci_l][rem] = v;
        }
        #pragma unroll
        for (int k = 0; k < 4; ++k) {
            int g = tid + k * 256;
            int ci_l = g >> 8; int rrem = g & 255;
            int co_l = rrem >> 2; int tg = (rrem & 3) * 4;
            int cico = (ci0 + ci_l) * COUT_ + co0 + co_l;
            int e = cico * 16 + tg;
            float4 w  = *(const float4*)(weight + e);
            float4 vb = *(const float4*)(tb + e);
            float4 vq = *(const float4*)(tq + e);
            float4 vn = *(const float4*)(tn + e);
            float4 vx = *(const float4*)(tx + e);
            float sb = mb[cico] * f0, sq = mq[cico] * f1;
            float sn = mn[cico] * f2, sx = mx[cico] * f3;
            float4 wvv;
            wvv.x = w.x + sb*vb.x + sq*vq.x + sn*vn.x + sx*vx.x;
            wvv.y = w.y + sb*vb.y + sq*vq.y + sn*vn.y + sx*vx.y;
            wvv.z = w.z + sb*vb.z + sq*vq.z + sn*vn.z + sx*vx.z;
            wvv.w = w.w + sb*vb.w + sq*vq.w + sn*vn.w + sx*vx.w;
            wsh[ci_l][tg + 0][co_l] = wvv.x;
            wsh[ci_l][tg + 1][co_l] = wvv.y;
            wsh[ci_l][tg + 2][co_l] = wvv.z;
            wsh[ci_l][tg + 3][co_l] = wvv.w;
        }
        __syncthreads();
        #pragma unroll
        for (int ci_l = 0; ci_l < 4; ++ci_l) {
            float xpv[4][4];
            #pragma unroll
            for (int i = 0; i < 4; ++i)
                #pragma unroll
                for (int j = 0; j < 4; ++j)
                    xpv[i][j] = xsf[ci_l][(rr*2 + i) * 10 + rc*2 + j];
            #pragma unroll
            for (int kh = 0; kh < 4; ++kh) {
                const int rpar = (kh & 1) ? 0 : 1;
                const int offh = (kh == 0) ? 2 : (kh == 3) ? 0 : 1;
                #pragma unroll
                for (int kw = 0; kw < 4; ++kw) {
                    const int spar = (kw & 1) ? 0 : 1;
                    const int offw = (kw == 0) ? 2 : (kw == 3) ? 0 : 1;
                    float4 wvv = *(const float4*)&wsh[ci_l][kh*4 + kw][tco*4];
                    float wr[4] = {wvv.x, wvv.y, wvv.z, wvv.w};
                    #pragma unroll
                    for (int da = 0; da < 2; ++da)
                        #pragma unroll
                        for (int dc = 0; dc < 2; ++dc) {
                            const float xvv = xpv[da + offh][dc + offw];
                            #pragma unroll
                            for (int cc = 0; cc < 4; ++cc)
                                acc[2*da + rpar][2*dc + spar][cc] =
                                    fmaf(wr[cc], xvv, acc[2*da + rpar][2*dc + spar][cc]);
                        }
                }
            }
        }
    }
    const float pa  = prelu_a[0];
    const int oh0 = tile_h * 16 + rr * 4;
    const int ow0 = tile_w * 16 + rc * 4;
    #pragma unroll
    for (int cc = 0; cc < 4; ++cc) {
        const int co = co0 + tco * 4 + cc;
        const float bv = bias[co];
        #pragma unroll
        for (int dr = 0; dr < 4; ++dr)
            #pragma unroll
            for (int dw2 = 0; dw2 < 4; ++dw2) {
                float v = acc[dr][dw2][cc] + bv;
                v = (v >= 0.f) ? v : pa * v;
                out[(((size_t)b * COUT_ + co) * OH_ + (oh0 + dr)) * OW_ + (ow0 + dw2)] = v;
            }
    }
}

extern "C" void kernel_launch(void* const* d_in, const int* in_sizes, int n_in,
                              void* d_out, int out_size, void* d_ws, size_t ws_size,
                              hipStream_t stream) {
    (void)in_sizes; (void)n_in; (void)out_size;
    const float* x      = (const float*)d_in[0];
    const float* feat   = (const float*)d_in[1];
    const float* weight = (const float*)d_in[2];
    const float* tb     = (const float*)d_in[3];
    const float* tq     = (const float*)d_in[4];
    const float* tn     = (const float*)d_in[5];
    const float* tx     = (const float*)d_in[6];
    const float* mb     = (const float*)d_in[7];
    const float* mq     = (const float*)d_in[8];
    const float* mn     = (const float*)d_in[9];
    const float* mx     = (const float*)d_in[10];
    const float* bias   = (const float*)d_in[11];
    const float* prelu  = (const float*)d_in[12];
    float* out = (float*)d_out;

    const size_t aws_sz = (size_t)B_ * 4 * 32 * 128 * AST * sizeof(short);  // 23.07 MB
    const size_t xt_sz  = (size_t)B_ * 32 * 66 * 66 * 8 * sizeof(short);    // 35.68 MB

    if (ws_size >= aws_sz + xt_sz) {
        short* aws = (short*)d_ws;
        short* xt  = (short*)((char*)d_ws + aws_sz);
        prep_fused<<<dim3(1056 + 512), 256, 0, stream>>>(
            x, weight, tb, tq, tn, tx, mb, mq, mn, mx, feat, aws, xt);
        deconv_mfma2<<<dim3(2048), 256, 0, stream>>>(
            aws, xt, bias, prelu, out);
    } else if (ws_size >= aws_sz) {
        short* aws = (short*)d_ws;
        synth_aws<<<dim3(32, 16), 256, 0, stream>>>(
            weight, tb, tq, tn, tx, mb, mq, mn, mx, feat, aws);
        deconv_mfma_gather<<<dim3(32, 4, 16), 256, 0, stream>>>(
            x, aws, bias, prelu, out);
    } else {
        deconv_fallback<<<dim3(64, 2, 16), 256, 0, stream>>>(
            x, weight, tb, tq, tn, tx, mb, mq, mn, mx, feat, bias, prelu, out);
    }
}